// Round 1
// baseline (2183.560 us; speedup 1.0000x reference)
//
#include <hip/hip_runtime.h>

// Seq2Seq GRU (B=1024, H=1024, IN=55->pad 64, 49 enc + 25 dec steps), bf16 MFMA.
// ws layout (bytes): Whh_bf 6291456 | Wih_bf 393216 | fc_bf 131072 | x_enc 6422528 |
//   hF[2] 2x4194304 | hA[2] 2x2097152 | inF[2] 2x262144 | inA[2] 2x131072  (~25.4 MB)

typedef unsigned short ushort_t;
typedef __bf16 bf16x8 __attribute__((ext_vector_type(8)));
typedef float f32x4 __attribute__((ext_vector_type(4)));

#define N1 3145728   // Whh elems
#define N2 196608    // Wih padded elems (3072*64)
#define N3 65536     // fc padded elems (64*1024)
#define N4 3211264   // x_enc elems (49*1024*64)
#define N5 65536     // inp0 elems (1024*64)
#define N6 1048576   // h0 elems (1024*1024)
#define NTOT (N1 + N2 + N3 + N4 + N5 + N6)

__device__ __forceinline__ ushort_t f2bf(float f) {
  union { float f; unsigned u; } x; x.f = f;
  unsigned r = x.u + 0x7fffu + ((x.u >> 16) & 1u);
  return (ushort_t)(r >> 16);
}

__device__ __forceinline__ float sigmf(float x) {
  return 1.f / (1.f + __expf(-x));
}
__device__ __forceinline__ float tanhf_(float x) {
  return 1.f - 2.f / (__expf(2.f * x) + 1.f);
}

__device__ __forceinline__ void gl_lds16(const ushort_t* g, ushort_t* l) {
  __builtin_amdgcn_global_load_lds(
      (const __attribute__((address_space(1))) void*)g,
      (__attribute__((address_space(3))) void*)l, 16, 0, 0);
}

__global__ void init_kernel(const float* __restrict__ enc, const float* __restrict__ dec,
                            const float* __restrict__ Wih, const float* __restrict__ Whh,
                            const float* __restrict__ fcw,
                            ushort_t* __restrict__ Whh_bf, ushort_t* __restrict__ Wih_bf,
                            ushort_t* __restrict__ fc_bf, ushort_t* __restrict__ x_enc,
                            float* __restrict__ inF0, ushort_t* __restrict__ inA0,
                            float* __restrict__ hF0, ushort_t* __restrict__ hA0) {
  int i = blockIdx.x * 256 + threadIdx.x;
  if (i < N1) { Whh_bf[i] = f2bf(Whh[i]); return; }
  i -= N1;
  if (i < N2) { int r = i >> 6, c = i & 63;
    Wih_bf[i] = (c < 55) ? f2bf(Wih[r * 55 + c]) : (ushort_t)0; return; }
  i -= N2;
  if (i < N3) { int r = i >> 10, c = i & 1023;
    fc_bf[i] = (r < 55) ? f2bf(fcw[r * 1024 + c]) : (ushort_t)0; return; }
  i -= N3;
  if (i < N4) { int t = i >> 16, rem = i & 65535, b = rem >> 6, c = rem & 63;
    x_enc[i] = (c < 55) ? f2bf(enc[(b * 50 + t) * 55 + c]) : (ushort_t)0; return; }
  i -= N4;
  if (i < N5) { int b = i >> 6, c = i & 63;
    float v = (c < 55) ? dec[b * 1375 + c] : 0.f;
    inF0[i] = v; inA0[i] = f2bf(v); return; }
  i -= N5;
  if (i < N6) { hF0[i] = 0.f; hA0[i] = 0; return; }
}

// One GRU step. Grid (16 j-tiles, 16 m-tiles), 256 threads (4 waves).
// Block computes 64(batch) x 64(hidden) of all 3 gates; K-loop: 32 iters over h
// (K=1024, BK=32) + 2 iters over x (K=64). n-gate keeps x-part / h-part separate.
__global__ __launch_bounds__(256, 2)
void gru_step(const ushort_t* __restrict__ hA, const float* __restrict__ hF,
              const ushort_t* __restrict__ X,
              const ushort_t* __restrict__ Whh, const ushort_t* __restrict__ Wih,
              const float* __restrict__ b_ih, const float* __restrict__ b_hh,
              float* __restrict__ hF_out, ushort_t* __restrict__ hA_out) {
  __shared__ ushort_t smem[2][8192];  // [A 64x32 | Br | Bz | Bn] per buffer
  const int tid = threadIdx.x;
  const int w = tid >> 6, l = tid & 63;
  const int m0 = blockIdx.y * 64, j0 = blockIdx.x * 64;
  const int idx = w * 64 + l;
  const int srow = idx >> 2, sc8 = (idx & 3) * 8;

  f32x4 aR[2][2], aZ[2][2], aNH[2][2], aNX[2][2];
#pragma unroll
  for (int mi = 0; mi < 2; ++mi)
#pragma unroll
    for (int ni = 0; ni < 2; ++ni) {
      aR[mi][ni] = (f32x4){0.f, 0.f, 0.f, 0.f};
      aZ[mi][ni] = (f32x4){0.f, 0.f, 0.f, 0.f};
      aNH[mi][ni] = (f32x4){0.f, 0.f, 0.f, 0.f};
      aNX[mi][ni] = (f32x4){0.f, 0.f, 0.f, 0.f};
    }

  auto stage = [&](int kt, int bsel) {
    ushort_t* buf = smem[bsel];
    if (kt < 32) {
      gl_lds16(hA + (m0 + srow) * 1024 + kt * 32 + sc8, buf + w * 512);
#pragma unroll
      for (int g = 0; g < 3; ++g)
        gl_lds16(Whh + (g * 1024 + j0 + srow) * 1024 + kt * 32 + sc8,
                 buf + (1 + g) * 2048 + w * 512);
    } else {
      const int q = (kt - 32) * 32;
      gl_lds16(X + (m0 + srow) * 64 + q + sc8, buf + w * 512);
#pragma unroll
      for (int g = 0; g < 3; ++g)
        gl_lds16(Wih + (g * 1024 + j0 + srow) * 64 + q + sc8,
                 buf + (1 + g) * 2048 + w * 512);
    }
  };

  const int r0 = (w >> 1) * 32, c0 = (w & 1) * 32;
  const int fr = l & 15, fq = (l >> 4) * 8;

  stage(0, 0);
  __syncthreads();
  for (int kt = 0; kt < 34; ++kt) {
    if (kt + 1 < 34) stage(kt + 1, (kt + 1) & 1);
    const ushort_t* buf = smem[kt & 1];
    bf16x8 a0 = *(const bf16x8*)(buf + (r0 + fr) * 32 + fq);
    bf16x8 a1 = *(const bf16x8*)(buf + (r0 + 16 + fr) * 32 + fq);
#pragma unroll
    for (int ni = 0; ni < 2; ++ni) {
      bf16x8 br = *(const bf16x8*)(buf + 2048 + (c0 + ni * 16 + fr) * 32 + fq);
      aR[0][ni] = __builtin_amdgcn_mfma_f32_16x16x32_bf16(a0, br, aR[0][ni], 0, 0, 0);
      aR[1][ni] = __builtin_amdgcn_mfma_f32_16x16x32_bf16(a1, br, aR[1][ni], 0, 0, 0);
      bf16x8 bz = *(const bf16x8*)(buf + 4096 + (c0 + ni * 16 + fr) * 32 + fq);
      aZ[0][ni] = __builtin_amdgcn_mfma_f32_16x16x32_bf16(a0, bz, aZ[0][ni], 0, 0, 0);
      aZ[1][ni] = __builtin_amdgcn_mfma_f32_16x16x32_bf16(a1, bz, aZ[1][ni], 0, 0, 0);
      bf16x8 bn = *(const bf16x8*)(buf + 6144 + (c0 + ni * 16 + fr) * 32 + fq);
      if (kt < 32) {
        aNH[0][ni] = __builtin_amdgcn_mfma_f32_16x16x32_bf16(a0, bn, aNH[0][ni], 0, 0, 0);
        aNH[1][ni] = __builtin_amdgcn_mfma_f32_16x16x32_bf16(a1, bn, aNH[1][ni], 0, 0, 0);
      } else {
        aNX[0][ni] = __builtin_amdgcn_mfma_f32_16x16x32_bf16(a0, bn, aNX[0][ni], 0, 0, 0);
        aNX[1][ni] = __builtin_amdgcn_mfma_f32_16x16x32_bf16(a1, bn, aNX[1][ni], 0, 0, 0);
      }
    }
    __syncthreads();
  }

  // Epilogue: gates + state update. C/D layout: col=lane&15, row=(lane>>4)*4+v.
#pragma unroll
  for (int ni = 0; ni < 2; ++ni) {
    const int jc = j0 + c0 + ni * 16 + fr;
    const float brz = b_ih[jc] + b_hh[jc];
    const float bzz = b_ih[1024 + jc] + b_hh[1024 + jc];
    const float bin = b_ih[2048 + jc];
    const float bhn = b_hh[2048 + jc];
#pragma unroll
    for (int mi = 0; mi < 2; ++mi) {
#pragma unroll
      for (int v = 0; v < 4; ++v) {
        const int bR = m0 + r0 + mi * 16 + (l >> 4) * 4 + v;
        float r = sigmf(aR[mi][ni][v] + brz);
        float z = sigmf(aZ[mi][ni][v] + bzz);
        float n = tanhf_(aNX[mi][ni][v] + bin + r * (aNH[mi][ni][v] + bhn));
        float hp = hF[bR * 1024 + jc];
        float hn2 = (1.f - z) * n + z * hp;
        hF_out[bR * 1024 + jc] = hn2;
        hA_out[bR * 1024 + jc] = f2bf(hn2);
      }
    }
  }
}

// Decoder output: out = inp + h_new @ fc_w^T + fc_b. Grid 16 m-tiles, 256 thr.
__global__ __launch_bounds__(256, 2)
void dec_out(const ushort_t* __restrict__ hA, const float* __restrict__ inpF,
             const ushort_t* __restrict__ fcW, const float* __restrict__ fc_b,
             float* __restrict__ dout, float* __restrict__ inpF_next,
             ushort_t* __restrict__ inpA_next) {
  __shared__ ushort_t smem[2][4096];
  const int tid = threadIdx.x;
  const int w = tid >> 6, l = tid & 63;
  const int m0 = blockIdx.x * 64;
  const int idx = w * 64 + l;
  const int srow = idx >> 2, sc8 = (idx & 3) * 8;

  f32x4 acc[2][2];
#pragma unroll
  for (int mi = 0; mi < 2; ++mi)
#pragma unroll
    for (int ni = 0; ni < 2; ++ni) acc[mi][ni] = (f32x4){0.f, 0.f, 0.f, 0.f};

  auto stage = [&](int kt, int bsel) {
    ushort_t* buf = smem[bsel];
    gl_lds16(hA + (m0 + srow) * 1024 + kt * 32 + sc8, buf + w * 512);
    gl_lds16(fcW + srow * 1024 + kt * 32 + sc8, buf + 2048 + w * 512);
  };

  const int r0 = (w >> 1) * 32, c0 = (w & 1) * 32;
  const int fr = l & 15, fq = (l >> 4) * 8;

  stage(0, 0);
  __syncthreads();
  for (int kt = 0; kt < 32; ++kt) {
    if (kt + 1 < 32) stage(kt + 1, (kt + 1) & 1);
    const ushort_t* buf = smem[kt & 1];
    bf16x8 a0 = *(const bf16x8*)(buf + (r0 + fr) * 32 + fq);
    bf16x8 a1 = *(const bf16x8*)(buf + (r0 + 16 + fr) * 32 + fq);
#pragma unroll
    for (int ni = 0; ni < 2; ++ni) {
      bf16x8 bb = *(const bf16x8*)(buf + 2048 + (c0 + ni * 16 + fr) * 32 + fq);
      acc[0][ni] = __builtin_amdgcn_mfma_f32_16x16x32_bf16(a0, bb, acc[0][ni], 0, 0, 0);
      acc[1][ni] = __builtin_amdgcn_mfma_f32_16x16x32_bf16(a1, bb, acc[1][ni], 0, 0, 0);
    }
    __syncthreads();
  }

#pragma unroll
  for (int ni = 0; ni < 2; ++ni) {
    const int jc = c0 + ni * 16 + fr;  // 0..63
    const float fb = (jc < 55) ? fc_b[jc] : 0.f;
#pragma unroll
    for (int mi = 0; mi < 2; ++mi) {
#pragma unroll
      for (int v = 0; v < 4; ++v) {
        const int bR = m0 + r0 + mi * 16 + (l >> 4) * 4 + v;
        float val = acc[mi][ni][v] + inpF[bR * 64 + jc] + fb;
        inpF_next[bR * 64 + jc] = val;
        inpA_next[bR * 64 + jc] = f2bf(val);
        if (jc < 55) dout[bR * 1375 + jc] = val;
      }
    }
  }
}

extern "C" void kernel_launch(void* const* d_in, const int* in_sizes, int n_in,
                              void* d_out, int out_size, void* d_ws, size_t ws_size,
                              hipStream_t stream) {
  const float* enc  = (const float*)d_in[0];
  const float* dec  = (const float*)d_in[1];
  const float* Wih  = (const float*)d_in[2];
  const float* Whh  = (const float*)d_in[3];
  const float* b_ih = (const float*)d_in[4];
  const float* b_hh = (const float*)d_in[5];
  const float* fcw  = (const float*)d_in[6];
  const float* fcb  = (const float*)d_in[7];
  float* out = (float*)d_out;

  char* ws = (char*)d_ws;
  ushort_t* Whh_bf = (ushort_t*)ws; ws += (size_t)3072 * 1024 * 2;
  ushort_t* Wih_bf = (ushort_t*)ws; ws += (size_t)3072 * 64 * 2;
  ushort_t* fc_bf  = (ushort_t*)ws; ws += (size_t)64 * 1024 * 2;
  ushort_t* x_enc  = (ushort_t*)ws; ws += (size_t)49 * 1024 * 64 * 2;
  float* hF0 = (float*)ws; ws += (size_t)1024 * 1024 * 4;
  float* hF1 = (float*)ws; ws += (size_t)1024 * 1024 * 4;
  ushort_t* hA0 = (ushort_t*)ws; ws += (size_t)1024 * 1024 * 2;
  ushort_t* hA1 = (ushort_t*)ws; ws += (size_t)1024 * 1024 * 2;
  float* inF0 = (float*)ws; ws += (size_t)1024 * 64 * 4;
  float* inF1 = (float*)ws; ws += (size_t)1024 * 64 * 4;
  ushort_t* inA0 = (ushort_t*)ws; ws += (size_t)1024 * 64 * 2;
  ushort_t* inA1 = (ushort_t*)ws; ws += (size_t)1024 * 64 * 2;
  float* hF[2] = {hF0, hF1};
  ushort_t* hA[2] = {hA0, hA1};
  float* inF[2] = {inF0, inF1};
  ushort_t* inA[2] = {inA0, inA1};

  init_kernel<<<(NTOT + 255) / 256, 256, 0, stream>>>(
      enc, dec, Wih, Whh, fcw, Whh_bf, Wih_bf, fc_bf, x_enc, inF0, inA0, hF0, hA0);

  int p = 0;
  for (int t = 0; t < 49; ++t) {
    gru_step<<<dim3(16, 16), 256, 0, stream>>>(
        hA[p], hF[p], x_enc + (size_t)t * 1024 * 64, Whh_bf, Wih_bf, b_ih, b_hh,
        hF[p ^ 1], hA[p ^ 1]);
    p ^= 1;
  }
  int q = 0;
  for (int t = 0; t < 25; ++t) {
    gru_step<<<dim3(16, 16), 256, 0, stream>>>(
        hA[p], hF[p], inA[q], Whh_bf, Wih_bf, b_ih, b_hh, hF[p ^ 1], hA[p ^ 1]);
    p ^= 1;
    dec_out<<<16, 256, 0, stream>>>(
        hA[p], inF[q], fc_bf, fcb, out + t * 55, inF[q ^ 1], inA[q ^ 1]);
    q ^= 1;
  }
}